// Round 1
// baseline (1132.147 us; speedup 1.0000x reference)
//
#include <hip/hip_runtime.h>

// LoRA Linear: out = x @ W^T + bias + (x @ a[idx]^T) @ b[idx]^T
// B=8, S=2048, D_IN=D_OUT=4096, RANK=16, N_ADAPTERS=8.
// Strategy: convert x,W to bf16 in d_ws, compute inter=x@a^T in fp32,
// then one 128x128-tile bf16 MFMA GEMM with the rank-16 LoRA fused as a
// single extra (zero-padded) MFMA K-step and bias in the epilogue.
// Workspace: x_bf16 128MiB + W_bf16 32MiB + inter 1MiB = 161MiB.

#define S_DIM   2048
#define DIN     4096
#define DOUT    4096
#define RANK    16
#define M_DIM   16384   // B*S
#define K_DIM   DIN
#define N_DIM   DOUT

typedef __attribute__((ext_vector_type(8))) short  short8;
typedef __attribute__((ext_vector_type(4))) float  floatx4;

__device__ __forceinline__ unsigned short f2bf(float f) {
  union { float f; unsigned int u; } v; v.f = f;
  // round-to-nearest-even; inputs are normal floats (no NaN guard needed)
  return (unsigned short)((v.u + 0x7FFFu + ((v.u >> 16) & 1u)) >> 16);
}
__device__ __forceinline__ unsigned int pk2(float a, float b) {
  return (unsigned int)f2bf(a) | ((unsigned int)f2bf(b) << 16);
}

// adapter_indices is int64 in the reference; harness contract says int32.
// int64 little-endian with values<8 looks like [v0,0,v1,0,...] as int32.
__device__ __forceinline__ int load_adapter(const int* __restrict__ p, int b) {
  bool i64 = (p[1] == 0) & (p[3] == 0) & (p[5] == 0) & (p[7] == 0);
  return i64 ? p[2 * b] : p[b];
}

__device__ __forceinline__ void async16(const unsigned short* g, unsigned short* s) {
  __builtin_amdgcn_global_load_lds(
      (const __attribute__((address_space(1))) void*)g,
      (__attribute__((address_space(3))) void*)s, 16, 0, 0);
}

// Pack 16 fp32 -> 16 bf16 into dst[0..15], zero dst[16..31] (K-pad for MFMA).
__device__ __forceinline__ void pack16_pad(const float* __restrict__ src,
                                           unsigned short* dst) {
  float4 v0 = ((const float4*)src)[0], v1 = ((const float4*)src)[1],
         v2 = ((const float4*)src)[2], v3 = ((const float4*)src)[3];
  uint4 p0, p1;
  p0.x = pk2(v0.x, v0.y); p0.y = pk2(v0.z, v0.w);
  p0.z = pk2(v1.x, v1.y); p0.w = pk2(v1.z, v1.w);
  p1.x = pk2(v2.x, v2.y); p1.y = pk2(v2.z, v2.w);
  p1.z = pk2(v3.x, v3.y); p1.w = pk2(v3.z, v3.w);
  ((uint4*)dst)[0] = p0;
  ((uint4*)dst)[1] = p1;
  uint4 z = make_uint4(0u, 0u, 0u, 0u);
  ((uint4*)dst)[2] = z;
  ((uint4*)dst)[3] = z;
}

// ---------- kernel 1: W fp32 -> bf16 ----------
__global__ __launch_bounds__(256) void conv_w(const float* __restrict__ w,
                                              unsigned short* __restrict__ wbf) {
  size_t base = ((size_t)blockIdx.x * 256 + threadIdx.x) * 8;
  const float4* src = (const float4*)(w + base);
  float4 f0 = src[0], f1 = src[1];
  uint4 p;
  p.x = pk2(f0.x, f0.y); p.y = pk2(f0.z, f0.w);
  p.z = pk2(f1.x, f1.y); p.w = pk2(f1.z, f1.w);
  *(uint4*)(wbf + base) = p;
}

// ---------- kernel 2: x fp32 -> bf16  AND  inter = x @ a[idx]^T (fp32) ----------
// 16 rows per block (all in one batch: 2048 % 16 == 0); lora_a chunk staged in LDS.
__global__ __launch_bounds__(256) void conv_x_inter(
    const float* __restrict__ x,
    const float* __restrict__ lora_a,
    const int* __restrict__ adapters,
    unsigned short* __restrict__ xbf,
    float* __restrict__ inter) {
  __shared__ float a_lds[RANK][256];
  const int tid  = threadIdx.x;
  const int row0 = blockIdx.x * 16;
  const int adapter = load_adapter(adapters, row0 >> 11);  // /2048
  const float* abase = lora_a + (size_t)adapter * RANK * DIN;
  const int rrow = tid >> 4;        // local row 0..15
  const int g    = tid & 15;        // k-subgroup within chunk
  const float* xrow = x + (size_t)(row0 + rrow) * DIN;
  unsigned short* xbrow = xbf + (size_t)(row0 + rrow) * DIN;

  float acc[RANK];
#pragma unroll
  for (int r = 0; r < RANK; ++r) acc[r] = 0.f;

  for (int kc = 0; kc < DIN; kc += 256) {
    __syncthreads();
    // cooperative load of a[0..15][kc..kc+255]: 4096 floats, 4x float4/thread
#pragma unroll
    for (int i = 0; i < 4; ++i) {
      int fl = i * 1024 + tid * 4;
      int r = fl >> 8, c = fl & 255;
      *(float4*)&a_lds[r][c] = *(const float4*)(abase + (size_t)r * DIN + kc + c);
    }
    __syncthreads();
    float4 xv[4];
#pragma unroll
    for (int i = 0; i < 4; ++i) {
      int c = g * 4 + i * 64;       // lanes 0..15 contiguous -> coalesced
      xv[i] = *(const float4*)(xrow + kc + c);
      uint2 pb; pb.x = pk2(xv[i].x, xv[i].y); pb.y = pk2(xv[i].z, xv[i].w);
      *(uint2*)(xbrow + kc + c) = pb;
    }
#pragma unroll
    for (int r = 0; r < RANK; ++r) {
      float s = acc[r];
#pragma unroll
      for (int i = 0; i < 4; ++i) {
        const float* ap = &a_lds[r][g * 4 + i * 64];
        s += xv[i].x * ap[0] + xv[i].y * ap[1] + xv[i].z * ap[2] + xv[i].w * ap[3];
      }
      acc[r] = s;
    }
  }
  // reduce across the 16 lanes sharing a row (butterfly, stays in-group)
#pragma unroll
  for (int m = 1; m < 16; m <<= 1)
#pragma unroll
    for (int r = 0; r < RANK; ++r) acc[r] += __shfl_xor(acc[r], m, 64);
  if (g == 0) {
    float* ip = inter + (size_t)(row0 + rrow) * RANK;
    float4 o;
    o.x = acc[0];  o.y = acc[1];  o.z = acc[2];  o.w = acc[3];  ((float4*)ip)[0] = o;
    o.x = acc[4];  o.y = acc[5];  o.z = acc[6];  o.w = acc[7];  ((float4*)ip)[1] = o;
    o.x = acc[8];  o.y = acc[9];  o.z = acc[10]; o.w = acc[11]; ((float4*)ip)[2] = o;
    o.x = acc[12]; o.y = acc[13]; o.z = acc[14]; o.w = acc[15]; ((float4*)ip)[3] = o;
  }
}

// ---------- kernel 3: bf16 MFMA GEMM + fused LoRA K-step + bias ----------
// 128x128 tile, BK=32, 4 waves in 2x2, each wave 64x64 (4x4 of 16x16x32 MFMA).
__global__ __launch_bounds__(256, 2) void gemm_lora(
    const unsigned short* __restrict__ A,    // x bf16 [M,K]
    const unsigned short* __restrict__ Bw,   // W bf16 [N,K] (row-major = B^T)
    const float* __restrict__ bias,          // [N]
    const float* __restrict__ inter,         // [M,16] fp32
    const float* __restrict__ lora_b,        // [8, N, 16] fp32
    const int* __restrict__ adapters,
    float* __restrict__ out) {               // [M,N] fp32
  __shared__ unsigned short As[128 * 32];    // 8 KiB
  __shared__ unsigned short Bs[128 * 32];    // 8 KiB
  const int tid = threadIdx.x;
  const int wave = tid >> 6, lane = tid & 63;
  const int wm = wave >> 1, wn = wave & 1;
  const int row0 = blockIdx.y * 128, col0 = blockIdx.x * 128;

  // global_load_lds staging: lane l covers LDS base + l*16B
  const int lrow = lane >> 2, lcol = (lane & 3) * 8;
  const unsigned short* ag = A  + (size_t)(row0 + wave * 32 + lrow) * K_DIM + lcol;
  const unsigned short* bg = Bw + (size_t)(col0 + wave * 32 + lrow) * K_DIM + lcol;
  unsigned short* asd = As + wave * 1024;   // wave stages rows [wave*32, +32)
  unsigned short* bsd = Bs + wave * 1024;

  // fragment read addresses (A[m=lane&15][k=quad*8+j], B mirrors with n)
  const int fr = lane & 15, fq = lane >> 4;
  const unsigned short* afp = As + ((wm * 64 + fr) * 32 + fq * 8);
  const unsigned short* bfp = Bs + ((wn * 64 + fr) * 32 + fq * 8);

  floatx4 acc[4][4] = {};

  for (int k0 = 0; k0 < K_DIM; k0 += 32) {
    __syncthreads();
    async16(ag + k0, asd);
    async16(ag + k0 + (size_t)16 * K_DIM, asd + 512);
    async16(bg + k0, bsd);
    async16(bg + k0 + (size_t)16 * K_DIM, bsd + 512);
    __syncthreads();   // barrier drains vmcnt -> LDS tile ready
    short8 af[4], bf[4];
#pragma unroll
    for (int i = 0; i < 4; ++i) af[i] = *(const short8*)(afp + i * 512);
#pragma unroll
    for (int i = 0; i < 4; ++i) bf[i] = *(const short8*)(bfp + i * 512);
#pragma unroll
    for (int mt = 0; mt < 4; ++mt)
#pragma unroll
      for (int nt = 0; nt < 4; ++nt)
        acc[mt][nt] = __builtin_amdgcn_mfma_f32_16x16x32_bf16(
            af[mt], bf[nt], acc[mt][nt], 0, 0, 0);
  }

  // ---- LoRA second stage as ONE extra MFMA K-step (k=16..31 zero-padded) ----
  const int adapter = load_adapter(adapters, row0 >> 11);  // block-uniform batch
  __syncthreads();  // last compute done before LDS overwrite
  if (tid < 128) {
    pack16_pad(inter + (size_t)(row0 + tid) * RANK, As + tid * 32);
  } else {
    int c = tid - 128;
    pack16_pad(lora_b + ((size_t)adapter * N_DIM + (col0 + c)) * RANK, Bs + c * 32);
  }
  __syncthreads();
  {
    short8 af[4], bf[4];
#pragma unroll
    for (int i = 0; i < 4; ++i) af[i] = *(const short8*)(afp + i * 512);
#pragma unroll
    for (int i = 0; i < 4; ++i) bf[i] = *(const short8*)(bfp + i * 512);
#pragma unroll
    for (int mt = 0; mt < 4; ++mt)
#pragma unroll
      for (int nt = 0; nt < 4; ++nt)
        acc[mt][nt] = __builtin_amdgcn_mfma_f32_16x16x32_bf16(
            af[mt], bf[nt], acc[mt][nt], 0, 0, 0);
  }

  // ---- epilogue: + bias, store (C/D layout: col=lane&15, row=quad*4+reg) ----
#pragma unroll
  for (int nt = 0; nt < 4; ++nt) {
    int col = col0 + wn * 64 + nt * 16 + fr;
    float bv = bias[col];
#pragma unroll
    for (int mt = 0; mt < 4; ++mt) {
      int row = row0 + wm * 64 + mt * 16 + fq * 4;
      float* op = out + (size_t)row * N_DIM + col;
#pragma unroll
      for (int j = 0; j < 4; ++j)
        op[(size_t)j * N_DIM] = acc[mt][nt][j] + bv;
    }
  }
}

extern "C" void kernel_launch(void* const* d_in, const int* in_sizes, int n_in,
                              void* d_out, int out_size, void* d_ws, size_t ws_size,
                              hipStream_t stream) {
  const float* x      = (const float*)d_in[0];
  const float* W      = (const float*)d_in[1];
  const float* bias   = (const float*)d_in[2];
  const float* lora_a = (const float*)d_in[3];
  const float* lora_b = (const float*)d_in[4];
  const int*   aidx   = (const int*)d_in[5];
  float* out = (float*)d_out;

  const size_t xbf_bytes = (size_t)M_DIM * DIN * 2;   // 128 MiB
  const size_t wbf_bytes = (size_t)N_DIM * DIN * 2;   //  32 MiB
  unsigned short* xbf = (unsigned short*)d_ws;
  unsigned short* wbf = (unsigned short*)((char*)d_ws + xbf_bytes);
  float* inter = (float*)((char*)d_ws + xbf_bytes + wbf_bytes);  // 1 MiB

  conv_w<<<dim3((size_t)N_DIM * DIN / (256 * 8)), dim3(256), 0, stream>>>(W, wbf);
  conv_x_inter<<<dim3(M_DIM / 16), dim3(256), 0, stream>>>(x, lora_a, aidx, xbf, inter);
  gemm_lora<<<dim3(N_DIM / 128, M_DIM / 128), dim3(256), 0, stream>>>(
      xbf, wbf, bias, inter, lora_b, aidx, out);
}

// Round 2
// 1123.104 us; speedup vs baseline: 1.0081x; 1.0081x over previous
//
#include <hip/hip_runtime.h>

// LoRA Linear: out = x @ W^T + bias + (x @ a[idx]^T) @ b[idx]^T
// B=8, S=2048, D_IN=D_OUT=4096, RANK=16, N_ADAPTERS=8.
// R2: conv path rebuilt. inter_conv_x fuses x fp32->bf16 streaming with the
// rank-16 inter GEMM done on the MFMA pipe (K-split 4 ways per 16-row group).
// gemm_lora kept byte-identical to R1 (m97-plateau structure, 36% MfmaUtil).
// Workspace: x_bf16 128MiB + W_bf16 32MiB + inter 1MiB = 161MiB.

#define S_DIM   2048
#define DIN     4096
#define DOUT    4096
#define RANK    16
#define M_DIM   16384   // B*S
#define K_DIM   DIN
#define N_DIM   DOUT

typedef __attribute__((ext_vector_type(8))) short  short8;
typedef __attribute__((ext_vector_type(4))) float  floatx4;

__device__ __forceinline__ unsigned short f2bf(float f) {
  union { float f; unsigned int u; } v; v.f = f;
  return (unsigned short)((v.u + 0x7FFFu + ((v.u >> 16) & 1u)) >> 16);
}
__device__ __forceinline__ unsigned int pk2(float a, float b) {
  return (unsigned int)f2bf(a) | ((unsigned int)f2bf(b) << 16);
}

// adapter_indices is int64 in the reference; harness contract says int32.
// int64 little-endian with values<8 looks like [v0,0,v1,0,...] as int32.
__device__ __forceinline__ int load_adapter(const int* __restrict__ p, int b) {
  bool i64 = (p[1] == 0) & (p[3] == 0) & (p[5] == 0) & (p[7] == 0);
  return i64 ? p[2 * b] : p[b];
}

__device__ __forceinline__ void async16(const unsigned short* g, unsigned short* s) {
  __builtin_amdgcn_global_load_lds(
      (const __attribute__((address_space(1))) void*)g,
      (__attribute__((address_space(3))) void*)s, 16, 0, 0);
}

// Pack 16 fp32 -> 16 bf16 into dst[0..15], zero dst[16..31] (K-pad for MFMA).
__device__ __forceinline__ void pack16_pad(const float* __restrict__ src,
                                           unsigned short* dst) {
  float4 v0 = ((const float4*)src)[0], v1 = ((const float4*)src)[1],
         v2 = ((const float4*)src)[2], v3 = ((const float4*)src)[3];
  uint4 p0, p1;
  p0.x = pk2(v0.x, v0.y); p0.y = pk2(v0.z, v0.w);
  p0.z = pk2(v1.x, v1.y); p0.w = pk2(v1.z, v1.w);
  p1.x = pk2(v2.x, v2.y); p1.y = pk2(v2.z, v2.w);
  p1.z = pk2(v3.x, v3.y); p1.w = pk2(v3.z, v3.w);
  ((uint4*)dst)[0] = p0;
  ((uint4*)dst)[1] = p1;
  uint4 z = make_uint4(0u, 0u, 0u, 0u);
  ((uint4*)dst)[2] = z;
  ((uint4*)dst)[3] = z;
}

// ---------- kernel 1: W fp32 -> bf16 (streaming, 8 elems/thread) ----------
__global__ __launch_bounds__(256) void conv_w(const float* __restrict__ w,
                                              unsigned short* __restrict__ wbf) {
  size_t base = ((size_t)blockIdx.x * 256 + threadIdx.x) * 8;
  const float4* src = (const float4*)(w + base);
  float4 f0 = src[0], f1 = src[1];
  uint4 p;
  p.x = pk2(f0.x, f0.y); p.y = pk2(f0.z, f0.w);
  p.z = pk2(f1.x, f1.y); p.w = pk2(f1.z, f1.w);
  *(uint4*)(wbf + base) = p;
}

// ---------- kernel 2: x fp32->bf16 streaming + inter = x @ a^T via MFMA ----
// One block per 16-row group; 4 waves split K (1024 each). Each lane owns
// row fr = lane&15, k-chunk fq = lane>>4 (matches 16x16x32 A/B frag layout
// A[m=lane&15][k=(lane>>4)*8+j], verified by R1's passing gemm).
__global__ __launch_bounds__(256) void inter_conv_x(
    const float* __restrict__ x,
    const float* __restrict__ lora_a,
    const int* __restrict__ adapters,
    unsigned short* __restrict__ xbf,
    float* __restrict__ inter) {
  __shared__ floatx4 red[4][64];
  const int tid = threadIdx.x, wave = tid >> 6, lane = tid & 63;
  const int fr = lane & 15, fq = lane >> 4;
  const int row0 = blockIdx.x * 16;
  const int adapter = load_adapter(adapters, row0 >> 11);  // 2048 rows/batch

  const float* xp = x + (size_t)(row0 + fr) * DIN;
  unsigned short* xq = xbf + (size_t)(row0 + fr) * DIN;
  const float* ap = lora_a + ((size_t)adapter * RANK + fr) * DIN;

  floatx4 acc = {};
  const int kbeg = wave * 1024, kend = kbeg + 1024;
  for (int k0 = kbeg; k0 < kend; k0 += 32) {
    const int k = k0 + fq * 8;
    // A: this row's 8 fp32 -> bf16, also persisted to xbf
    float4 a0 = *(const float4*)(xp + k);
    float4 a1 = *(const float4*)(xp + k + 4);
    uint4 apk;
    apk.x = pk2(a0.x, a0.y); apk.y = pk2(a0.z, a0.w);
    apk.z = pk2(a1.x, a1.y); apk.w = pk2(a1.z, a1.w);
    *(uint4*)(xq + k) = apk;
    // B: lora_a row fr (rank), same 8 k (L2-resident, 2 MB total)
    float4 b0 = *(const float4*)(ap + k);
    float4 b1 = *(const float4*)(ap + k + 4);
    uint4 bpk;
    bpk.x = pk2(b0.x, b0.y); bpk.y = pk2(b0.z, b0.w);
    bpk.z = pk2(b1.x, b1.y); bpk.w = pk2(b1.z, b1.w);
    short8 af = *(short8*)&apk;
    short8 bf_ = *(short8*)&bpk;
    acc = __builtin_amdgcn_mfma_f32_16x16x32_bf16(af, bf_, acc, 0, 0, 0);
  }
  red[wave][lane] = acc;
  __syncthreads();
  if (wave == 0) {
    floatx4 s = red[0][lane] + red[1][lane] + red[2][lane] + red[3][lane];
    // C/D layout: col(rank)=lane&15, row=fq*4+j
#pragma unroll
    for (int j = 0; j < 4; ++j)
      inter[(size_t)(row0 + fq * 4 + j) * RANK + fr] = s[j];
  }
}

// ---------- kernel 3: bf16 MFMA GEMM + fused LoRA K-step + bias ----------
// 128x128 tile, BK=32, 4 waves in 2x2, each wave 64x64 (4x4 of 16x16x32 MFMA).
// UNCHANGED from R1 (703 us, MfmaUtil 36% -- m97 structural plateau).
__global__ __launch_bounds__(256, 2) void gemm_lora(
    const unsigned short* __restrict__ A,    // x bf16 [M,K]
    const unsigned short* __restrict__ Bw,   // W bf16 [N,K] (row-major = B^T)
    const float* __restrict__ bias,          // [N]
    const float* __restrict__ inter,         // [M,16] fp32
    const float* __restrict__ lora_b,        // [8, N, 16] fp32
    const int* __restrict__ adapters,
    float* __restrict__ out) {               // [M,N] fp32
  __shared__ unsigned short As[128 * 32];    // 8 KiB
  __shared__ unsigned short Bs[128 * 32];    // 8 KiB
  const int tid = threadIdx.x;
  const int wave = tid >> 6, lane = tid & 63;
  const int wm = wave >> 1, wn = wave & 1;
  const int row0 = blockIdx.y * 128, col0 = blockIdx.x * 128;

  const int lrow = lane >> 2, lcol = (lane & 3) * 8;
  const unsigned short* ag = A  + (size_t)(row0 + wave * 32 + lrow) * K_DIM + lcol;
  const unsigned short* bg = Bw + (size_t)(col0 + wave * 32 + lrow) * K_DIM + lcol;
  unsigned short* asd = As + wave * 1024;
  unsigned short* bsd = Bs + wave * 1024;

  const int fr = lane & 15, fq = lane >> 4;
  const unsigned short* afp = As + ((wm * 64 + fr) * 32 + fq * 8);
  const unsigned short* bfp = Bs + ((wn * 64 + fr) * 32 + fq * 8);

  floatx4 acc[4][4] = {};

  for (int k0 = 0; k0 < K_DIM; k0 += 32) {
    __syncthreads();
    async16(ag + k0, asd);
    async16(ag + k0 + (size_t)16 * K_DIM, asd + 512);
    async16(bg + k0, bsd);
    async16(bg + k0 + (size_t)16 * K_DIM, bsd + 512);
    __syncthreads();
    short8 af[4], bf[4];
#pragma unroll
    for (int i = 0; i < 4; ++i) af[i] = *(const short8*)(afp + i * 512);
#pragma unroll
    for (int i = 0; i < 4; ++i) bf[i] = *(const short8*)(bfp + i * 512);
#pragma unroll
    for (int mt = 0; mt < 4; ++mt)
#pragma unroll
      for (int nt = 0; nt < 4; ++nt)
        acc[mt][nt] = __builtin_amdgcn_mfma_f32_16x16x32_bf16(
            af[mt], bf[nt], acc[mt][nt], 0, 0, 0);
  }

  // LoRA second stage as ONE extra MFMA K-step (k=16..31 zero-padded)
  const int adapter = load_adapter(adapters, row0 >> 11);
  __syncthreads();
  if (tid < 128) {
    pack16_pad(inter + (size_t)(row0 + tid) * RANK, As + tid * 32);
  } else {
    int c = tid - 128;
    pack16_pad(lora_b + ((size_t)adapter * N_DIM + (col0 + c)) * RANK, Bs + c * 32);
  }
  __syncthreads();
  {
    short8 af[4], bf[4];
#pragma unroll
    for (int i = 0; i < 4; ++i) af[i] = *(const short8*)(afp + i * 512);
#pragma unroll
    for (int i = 0; i < 4; ++i) bf[i] = *(const short8*)(bfp + i * 512);
#pragma unroll
    for (int mt = 0; mt < 4; ++mt)
#pragma unroll
      for (int nt = 0; nt < 4; ++nt)
        acc[mt][nt] = __builtin_amdgcn_mfma_f32_16x16x32_bf16(
            af[mt], bf[nt], acc[mt][nt], 0, 0, 0);
  }

  // epilogue: + bias, store (C/D layout: col=lane&15, row=quad*4+reg)
#pragma unroll
  for (int nt = 0; nt < 4; ++nt) {
    int col = col0 + wn * 64 + nt * 16 + fr;
    float bv = bias[col];
#pragma unroll
    for (int mt = 0; mt < 4; ++mt) {
      int row = row0 + wm * 64 + mt * 16 + fq * 4;
      float* op = out + (size_t)row * N_DIM + col;
#pragma unroll
      for (int j = 0; j < 4; ++j)
        op[(size_t)j * N_DIM] = acc[mt][nt][j] + bv;
    }
  }
}

extern "C" void kernel_launch(void* const* d_in, const int* in_sizes, int n_in,
                              void* d_out, int out_size, void* d_ws, size_t ws_size,
                              hipStream_t stream) {
  const float* x      = (const float*)d_in[0];
  const float* W      = (const float*)d_in[1];
  const float* bias   = (const float*)d_in[2];
  const float* lora_a = (const float*)d_in[3];
  const float* lora_b = (const float*)d_in[4];
  const int*   aidx   = (const int*)d_in[5];
  float* out = (float*)d_out;

  const size_t xbf_bytes = (size_t)M_DIM * DIN * 2;   // 128 MiB
  const size_t wbf_bytes = (size_t)N_DIM * DIN * 2;   //  32 MiB
  unsigned short* xbf = (unsigned short*)d_ws;
  unsigned short* wbf = (unsigned short*)((char*)d_ws + xbf_bytes);
  float* inter = (float*)((char*)d_ws + xbf_bytes + wbf_bytes);  // 1 MiB

  conv_w<<<dim3((size_t)N_DIM * DIN / (256 * 8)), dim3(256), 0, stream>>>(W, wbf);
  inter_conv_x<<<dim3(M_DIM / 16), dim3(256), 0, stream>>>(x, lora_a, aidx, xbf, inter);
  gemm_lora<<<dim3(N_DIM / 128, M_DIM / 128), dim3(256), 0, stream>>>(
      xbf, wbf, bias, inter, lora_b, aidx, out);
}